// Round 4
// baseline (595.920 us; speedup 1.0000x reference)
//
#include <hip/hip_runtime.h>
#include <hip/hip_cooperative_groups.h>
#include <stdint.h>

namespace cg = cooperative_groups;

// Problem constants
constexpr int ROWS = 64;
constexpr int D = 1 << 19;           // 524288 per row
constexpr uint32_t KSEL = 52428;     // int(0.1 * D)
constexpr int BLOCKS = 1024;         // cooperative grid: exactly 4 blocks/CU on 256 CUs
constexpr int BPR = BLOCKS / ROWS;   // 16 blocks per row
constexpr int CHUNK = D / BPR;       // 32768 elements per block
constexpr uint32_t CAND_MAX = 32768; // per-row candidate cap (expected ~11.5K)
constexpr int LBUF = 4096;           // per-block candidate cap (expected ~720)

// Workspace layout (u32 indices)
constexpr size_t OFF_HIST = 0;                       // 64*4096
constexpr size_t OFF_CNT  = OFF_HIST + ROWS * 4096;  // 64
constexpr size_t OFF_SEL  = OFF_CNT + 64;            // 64
constexpr size_t OFF_RANK = OFF_SEL + 64;            // 64
constexpr size_t OFF_THR  = OFF_RANK + 64;           // 64
constexpr size_t OFF_CAND = OFF_THR + 64;            // 64*CAND_MAX (~8.4 MB)
constexpr size_t ZERO_U32 = OFF_CNT + 64;            // hist + cnt zeroed each call

// Monotonic key: larger float -> larger uint
__device__ __forceinline__ uint32_t mono(uint32_t f) {
    uint32_t m = (uint32_t)((int32_t)f >> 31) | 0x80000000u;
    return f ^ m;
}

__global__ __launch_bounds__(256, 4) void wta_all(const uint32_t* __restrict__ x,
                                                  float* __restrict__ out,
                                                  uint32_t* __restrict__ ws) {
    cg::grid_group grid = cg::this_grid();
    __shared__ uint32_t smem[4096];   // hist / candidate buf / radix hist (reused)
    __shared__ uint32_t sc[256];
    __shared__ uint32_t bcast[2];
    __shared__ uint32_t ln, gbase;

    const int bid = blockIdx.x, t = threadIdx.x;
    const int row = bid / BPR, chunk = bid % BPR;
    const uint32_t* xrow = x + (size_t)row * D + (size_t)chunk * CHUNK;

    // ---- Phase 0: zero hist + cnt (1 MB spread over 1024 blocks) ----
    {
        uint4* p = (uint4*)ws;
        const size_t n4 = ZERO_U32 / 4;
        for (size_t i = (size_t)bid * 256 + t; i < n4; i += (size_t)BLOCKS * 256)
            p[i] = make_uint4(0, 0, 0, 0);
    }
    grid.sync();

    // ---- Phase A: per-row 12-bit histogram of key top bits ----
    for (int i = t; i < 4096; i += 256) smem[i] = 0;
    __syncthreads();
    const uint4* p4 = (const uint4*)xrow;
    for (int i = t; i < CHUNK / 4; i += 256) {
        uint4 v = p4[i];
        atomicAdd(&smem[mono(v.x) >> 20], 1u);
        atomicAdd(&smem[mono(v.y) >> 20], 1u);
        atomicAdd(&smem[mono(v.z) >> 20], 1u);
        atomicAdd(&smem[mono(v.w) >> 20], 1u);
    }
    __syncthreads();
    {
        uint32_t* h = ws + OFF_HIST + (size_t)row * 4096;
        for (int i = t; i < 4096; i += 256) {
            uint32_t c = smem[i];
            if (c) atomicAdd(&h[i], c);
        }
    }
    grid.sync();

    // ---- Phase B: per-row select over 4096 bins (blocks 0..63) ----
    if (bid < ROWS) {
        const uint32_t* h = ws + OFF_HIST + (size_t)bid * 4096;
        constexpr int PER = 16;
        int hi = 4095 - t * PER;  // descending ownership
        uint32_t s = 0;
        for (int j = 0; j < PER; ++j) s += h[hi - j];
        sc[t] = s;
        __syncthreads();
        for (int off = 1; off < 256; off <<= 1) {
            uint32_t v = (t >= off) ? sc[t - off] : 0u;
            __syncthreads();
            sc[t] += v;
            __syncthreads();
        }
        uint32_t excl = sc[t] - s;  // count strictly above this thread's group
        if (excl < KSEL && excl + s >= KSEL) {
            uint32_t c = excl;
            for (int j = 0; j < PER; ++j) {
                int bin = hi - j;
                uint32_t hb = h[bin];
                c += hb;
                if (c >= KSEL) {
                    ws[OFF_SEL + bid] = (uint32_t)bin;
                    ws[OFF_RANK + bid] = KSEL - (c - hb);  // in-bucket rank, 1-based
                    break;
                }
            }
        }
    }
    grid.sync();

    // ---- Phase C: compact keys in the selected bucket (L3-resident re-read) ----
    if (t == 0) ln = 0;
    __syncthreads();
    {
        uint32_t sb = ws[OFF_SEL + row];
        for (int i = t; i < CHUNK / 4; i += 256) {
            uint4 v = p4[i];
            uint32_t u;
#define PROC(c)                                                          \
            u = mono(c);                                                 \
            if ((u >> 20) == sb) {                                       \
                uint32_t s = atomicAdd(&ln, 1u);                         \
                if (s < (uint32_t)LBUF) smem[s] = u;                     \
            }
            PROC(v.x) PROC(v.y) PROC(v.z) PROC(v.w)
#undef PROC
        }
    }
    __syncthreads();
    {
        uint32_t m = ln < (uint32_t)LBUF ? ln : (uint32_t)LBUF;
        if (t == 0) gbase = atomicAdd(&ws[OFF_CNT + row], m);
        __syncthreads();
        uint32_t base = gbase;
        uint32_t* cand = ws + OFF_CAND + (size_t)row * CAND_MAX;
        for (uint32_t i = t; i < m; i += 256) {
            uint32_t slot = base + i;
            if (slot < CAND_MAX) cand[slot] = smem[i];
        }
    }
    grid.sync();

    // ---- Phase D: exact select among candidates, two 10-bit radix levels ----
    if (bid < ROWS) {
        uint32_t n = ws[OFF_CNT + bid];
        if (n > CAND_MAX) n = CAND_MAX;
        const uint32_t* c = ws + OFF_CAND + (size_t)bid * CAND_MAX;
        uint32_t k = ws[OFF_RANK + bid];
        uint32_t sb = ws[OFF_SEL + bid];

        // Level 1: bits 19..10
        for (int i = t; i < 1024; i += 256) smem[i] = 0;
        __syncthreads();
        for (uint32_t i = t; i < n; i += 256) atomicAdd(&smem[(c[i] >> 10) & 0x3FFu], 1u);
        __syncthreads();
        {
            int hi = 1023 - t * 4;
            uint32_t s = 0;
            for (int j = 0; j < 4; ++j) s += smem[hi - j];
            sc[t] = s;
            __syncthreads();
            for (int off = 1; off < 256; off <<= 1) {
                uint32_t v = (t >= off) ? sc[t - off] : 0u;
                __syncthreads();
                sc[t] += v;
                __syncthreads();
            }
            uint32_t excl = sc[t] - s;
            if (excl < k && excl + s >= k) {
                uint32_t cc = excl;
                for (int j = 0; j < 4; ++j) {
                    int bin = hi - j;
                    uint32_t hb = smem[bin];
                    cc += hb;
                    if (cc >= k) { bcast[0] = (uint32_t)bin; bcast[1] = k - (cc - hb); break; }
                }
            }
        }
        __syncthreads();
        uint32_t b1 = bcast[0], k2 = bcast[1];
        __syncthreads();

        // Level 2: bits 9..0 among candidates matching b1
        for (int i = t; i < 1024; i += 256) smem[i] = 0;
        __syncthreads();
        for (uint32_t i = t; i < n; i += 256) {
            uint32_t u = c[i];
            if (((u >> 10) & 0x3FFu) == b1) atomicAdd(&smem[u & 0x3FFu], 1u);
        }
        __syncthreads();
        {
            int hi = 1023 - t * 4;
            uint32_t s = 0;
            for (int j = 0; j < 4; ++j) s += smem[hi - j];
            sc[t] = s;
            __syncthreads();
            for (int off = 1; off < 256; off <<= 1) {
                uint32_t v = (t >= off) ? sc[t - off] : 0u;
                __syncthreads();
                sc[t] += v;
                __syncthreads();
            }
            uint32_t excl = sc[t] - s;
            if (excl < k2 && excl + s >= k2) {
                uint32_t cc = excl;
                for (int j = 0; j < 4; ++j) {
                    int bin = hi - j;
                    uint32_t hb = smem[bin];
                    cc += hb;
                    if (cc >= k2) {
                        uint32_t u = (sb << 20) | (b1 << 10) | (uint32_t)bin;
                        uint32_t m = (u & 0x80000000u) ? 0x80000000u : 0xFFFFFFFFu;
                        ws[OFF_THR + bid] = u ^ m;  // float bits of exact K-th largest
                        break;
                    }
                }
            }
        }
    }
    grid.sync();

    // ---- Phase E: masked write-out (x L3-resident; out to HBM) ----
    {
        float tv = __uint_as_float(ws[OFF_THR + row]);
        const float4* xf = (const float4*)xrow;
        float4* of = (float4*)(out + (size_t)row * D + (size_t)chunk * CHUNK);
        for (int i = t; i < CHUNK / 4; i += 256) {
            float4 v = xf[i];
            v.x = (v.x < tv) ? v.x : 0.0f;
            v.y = (v.y < tv) ? v.y : 0.0f;
            v.z = (v.z < tv) ? v.z : 0.0f;
            v.w = (v.w < tv) ? v.w : 0.0f;
            of[i] = v;
        }
    }
}

extern "C" void kernel_launch(void* const* d_in, const int* in_sizes, int n_in,
                              void* d_out, int out_size, void* d_ws, size_t ws_size,
                              hipStream_t stream) {
    (void)in_sizes; (void)n_in; (void)out_size; (void)ws_size;
    const uint32_t* xu = (const uint32_t*)d_in[0];
    float* outp = (float*)d_out;
    uint32_t* wsp = (uint32_t*)d_ws;

    void* args[] = { (void*)&xu, (void*)&outp, (void*)&wsp };
    hipLaunchCooperativeKernel(reinterpret_cast<void*>(wta_all),
                               dim3(BLOCKS), dim3(256), args, 0, stream);
}

// Round 5
// 125.190 us; speedup vs baseline: 4.7601x; 4.7601x over previous
//
#include <hip/hip_runtime.h>
#include <stdint.h>

// Problem constants
constexpr int ROWS = 64;
constexpr int D = 1 << 19;            // 524288 per row
constexpr uint32_t KSEL = 52428;      // int(0.1 * D)
constexpr int BPR = 32;               // blocks per row for full-pass kernels
constexpr int CHUNK = D / BPR;        // 16384 elements per block
constexpr uint32_t CAND_MAX = 16384;  // per-row candidate cap (expected ~11.5K, +46 sigma)
constexpr int LBUF = 2048;            // per-block candidate cap (expected ~360, +32 sigma)

// Workspace layout (u32 indices)
constexpr size_t OFF_HIST = 0;                         // 64*4096
constexpr size_t OFF_CNT  = OFF_HIST + ROWS * 4096;    // 64
constexpr size_t OFF_SEL  = OFF_CNT + 64;              // 64 (rewritten every call)
constexpr size_t OFF_RANK = OFF_SEL + 64;              // 64 (rewritten every call)
constexpr size_t OFF_CKEY = OFF_RANK + 64;             // 64*CAND_MAX keys
constexpr size_t OFF_CIDX = OFF_CKEY + ROWS * CAND_MAX;// 64*CAND_MAX row-local indices
constexpr size_t ZERO_U32 = OFF_CNT + 64;              // hist + cnt zeroed each call

// Monotonic key: larger float -> larger uint
__device__ __forceinline__ uint32_t mono(uint32_t f) {
    uint32_t m = (uint32_t)((int32_t)f >> 31) | 0x80000000u;
    return f ^ m;
}

__global__ __launch_bounds__(256) void zero_ws(uint32_t* __restrict__ ws) {
    const size_t n4 = ZERO_U32 / 4;  // 1 MB + 256 B, 16B-aligned count
    uint4* p = (uint4*)ws;
    for (size_t i = (size_t)blockIdx.x * 256 + threadIdx.x; i < n4;
         i += (size_t)gridDim.x * 256)
        p[i] = make_uint4(0, 0, 0, 0);
}

// Pass 1: per-row 12-bit histogram of key top bits (LDS-privatized).
__global__ __launch_bounds__(256) void hist_pass(const uint32_t* __restrict__ x,
                                                 uint32_t* __restrict__ ws) {
    __shared__ uint32_t lh[4096];
    for (int i = threadIdx.x; i < 4096; i += 256) lh[i] = 0;
    __syncthreads();
    int row = blockIdx.x / BPR, chunk = blockIdx.x % BPR;
    const uint4* p = (const uint4*)(x + (size_t)row * D + (size_t)chunk * CHUNK);
    for (int i = threadIdx.x; i < CHUNK / 4; i += 256) {
        uint4 v = p[i];
        atomicAdd(&lh[mono(v.x) >> 20], 1u);
        atomicAdd(&lh[mono(v.y) >> 20], 1u);
        atomicAdd(&lh[mono(v.z) >> 20], 1u);
        atomicAdd(&lh[mono(v.w) >> 20], 1u);
    }
    __syncthreads();
    uint32_t* h = ws + OFF_HIST + (size_t)row * 4096;
    for (int i = threadIdx.x; i < 4096; i += 256) {
        uint32_t c = lh[i];
        if (c) atomicAdd(&h[i], c);
    }
}

// Per-row select over 4096 bins (descending): exact bucket of the K-th
// largest + in-bucket rank (1-based).
__global__ __launch_bounds__(256) void select1(uint32_t* __restrict__ ws) {
    constexpr int PER = 16;
    __shared__ uint32_t sc[256];
    int row = blockIdx.x, t = threadIdx.x;
    const uint32_t* h = ws + OFF_HIST + (size_t)row * 4096;
    int hi = 4095 - t * PER;
    uint32_t s = 0;
    for (int j = 0; j < PER; ++j) s += h[hi - j];
    sc[t] = s;
    __syncthreads();
    for (int off = 1; off < 256; off <<= 1) {
        uint32_t v = (t >= off) ? sc[t - off] : 0u;
        __syncthreads();
        sc[t] += v;
        __syncthreads();
    }
    uint32_t excl = sc[t] - s;  // count strictly above this thread's bins
    if (excl < KSEL && excl + s >= KSEL) {
        uint32_t c = excl;
        for (int j = 0; j < PER; ++j) {
            int bin = hi - j;
            uint32_t hb = h[bin];
            c += hb;
            if (c >= KSEL) {
                ws[OFF_SEL + row] = (uint32_t)bin;
                ws[OFF_RANK + row] = KSEL - (c - hb);
                break;
            }
        }
    }
}

// Fused mask + candidate compaction. Classification vs threshold bucket b:
//   bucket > b  -> definitely >= thr -> out = 0
//   bucket < b  -> definitely <  thr -> out = x
//   bucket == b -> candidate: out = x provisionally; append (key, idx)
//                  (fixup kernel zeroes those with key >= thr_key)
__global__ __launch_bounds__(256) void mask_compact(const uint32_t* __restrict__ x,
                                                    float* __restrict__ out,
                                                    uint32_t* __restrict__ ws) {
    __shared__ uint32_t lkey[LBUF];
    __shared__ uint32_t lidx[LBUF];
    __shared__ uint32_t ln, gbase;
    if (threadIdx.x == 0) ln = 0;
    __syncthreads();
    int row = blockIdx.x / BPR, chunk = blockIdx.x % BPR;
    uint32_t b = ws[OFF_SEL + row];
    uint32_t lane = threadIdx.x & 63;
    uint64_t lt_mask = ((uint64_t)1 << lane) - 1;
    const uint4* p = (const uint4*)(x + (size_t)row * D + (size_t)chunk * CHUNK);
    float4* o = (float4*)(out + (size_t)row * D + (size_t)chunk * CHUNK);
    for (int i = threadIdx.x; i < CHUNK / 4; i += 256) {
        uint4 v = p[i];
        float4 ov;
        uint32_t idx0 = (uint32_t)chunk * CHUNK + (uint32_t)i * 4;
#define PROC(comp, oc, j)                                                     \
        {                                                                     \
            uint32_t u = mono(comp);                                          \
            uint32_t bu = u >> 20;                                            \
            oc = (bu > b) ? 0.0f : __uint_as_float(comp);                     \
            bool m = (bu == b);                                               \
            uint64_t bal = __ballot(m);                                       \
            if (bal) {                                                        \
                int lead = __ffsll((unsigned long long)bal) - 1;              \
                uint32_t base = 0;                                            \
                if ((int)lane == lead)                                        \
                    base = atomicAdd(&ln, (uint32_t)__popcll(bal));           \
                base = __shfl(base, lead, 64);                                \
                if (m) {                                                      \
                    uint32_t slot = base + (uint32_t)__popcll(bal & lt_mask); \
                    if (slot < (uint32_t)LBUF) {                              \
                        lkey[slot] = u;                                       \
                        lidx[slot] = idx0 + j;                                \
                    }                                                         \
                }                                                             \
            }                                                                 \
        }
        PROC(v.x, ov.x, 0)
        PROC(v.y, ov.y, 1)
        PROC(v.z, ov.z, 2)
        PROC(v.w, ov.w, 3)
#undef PROC
        o[i] = ov;
    }
    __syncthreads();
    uint32_t m = ln < (uint32_t)LBUF ? ln : (uint32_t)LBUF;
    if (threadIdx.x == 0) gbase = atomicAdd(&ws[OFF_CNT + row], m);
    __syncthreads();
    uint32_t base = gbase;
    uint32_t* ck = ws + OFF_CKEY + (size_t)row * CAND_MAX;
    uint32_t* ci = ws + OFF_CIDX + (size_t)row * CAND_MAX;
    for (uint32_t i = threadIdx.x; i < m; i += 256) {
        uint32_t slot = base + i;
        if (slot < CAND_MAX) { ck[slot] = lkey[i]; ci[slot] = lidx[i]; }
    }
}

// One block per row: radix-select exact threshold key among candidates
// (two 10-bit levels over low 20 bits), then scatter-zero candidates with
// key >= thr_key.
__global__ __launch_bounds__(256) void select_fix(float* __restrict__ out,
                                                  uint32_t* __restrict__ ws) {
    __shared__ uint32_t h[1024];
    __shared__ uint32_t sc[256];
    __shared__ uint32_t bcast[2];
    int row = blockIdx.x, t = threadIdx.x;
    uint32_t n = ws[OFF_CNT + row];
    if (n > CAND_MAX) n = CAND_MAX;
    const uint32_t* ck = ws + OFF_CKEY + (size_t)row * CAND_MAX;
    const uint32_t* ci = ws + OFF_CIDX + (size_t)row * CAND_MAX;
    uint32_t k = ws[OFF_RANK + row];
    uint32_t b = ws[OFF_SEL + row];

    // Level 1: bits 19..10
    for (int i = t; i < 1024; i += 256) h[i] = 0;
    __syncthreads();
    for (uint32_t i = t; i < n; i += 256) atomicAdd(&h[(ck[i] >> 10) & 0x3FFu], 1u);
    __syncthreads();
    {
        int hi = 1023 - t * 4;
        uint32_t s = 0;
        for (int j = 0; j < 4; ++j) s += h[hi - j];
        sc[t] = s;
        __syncthreads();
        for (int off = 1; off < 256; off <<= 1) {
            uint32_t v = (t >= off) ? sc[t - off] : 0u;
            __syncthreads();
            sc[t] += v;
            __syncthreads();
        }
        uint32_t excl = sc[t] - s;
        if (excl < k && excl + s >= k) {
            uint32_t cc = excl;
            for (int j = 0; j < 4; ++j) {
                int bin = hi - j;
                uint32_t hb = h[bin];
                cc += hb;
                if (cc >= k) { bcast[0] = (uint32_t)bin; bcast[1] = k - (cc - hb); break; }
            }
        }
    }
    __syncthreads();
    uint32_t b1 = bcast[0], k2 = bcast[1];
    __syncthreads();

    // Level 2: bits 9..0 among candidates matching b1
    for (int i = t; i < 1024; i += 256) h[i] = 0;
    __syncthreads();
    for (uint32_t i = t; i < n; i += 256) {
        uint32_t u = ck[i];
        if (((u >> 10) & 0x3FFu) == b1) atomicAdd(&h[u & 0x3FFu], 1u);
    }
    __syncthreads();
    {
        int hi = 1023 - t * 4;
        uint32_t s = 0;
        for (int j = 0; j < 4; ++j) s += h[hi - j];
        sc[t] = s;
        __syncthreads();
        for (int off = 1; off < 256; off <<= 1) {
            uint32_t v = (t >= off) ? sc[t - off] : 0u;
            __syncthreads();
            sc[t] += v;
            __syncthreads();
        }
        uint32_t excl = sc[t] - s;
        if (excl < k2 && excl + s >= k2) {
            uint32_t cc = excl;
            for (int j = 0; j < 4; ++j) {
                int bin = hi - j;
                uint32_t hb = h[bin];
                cc += hb;
                if (cc >= k2) {
                    bcast[0] = (b << 20) | (b1 << 10) | (uint32_t)bin;  // thr_key
                    break;
                }
            }
        }
    }
    __syncthreads();
    uint32_t thr_key = bcast[0];

    // Fixup: zero all candidates with key >= thr_key (exact tie handling:
    // reference zeroes x where x >= thr, and mono preserves order).
    float* orow = out + (size_t)row * D;
    for (uint32_t i = t; i < n; i += 256) {
        if (ck[i] >= thr_key) orow[ci[i]] = 0.0f;
    }
}

extern "C" void kernel_launch(void* const* d_in, const int* in_sizes, int n_in,
                              void* d_out, int out_size, void* d_ws, size_t ws_size,
                              hipStream_t stream) {
    (void)in_sizes; (void)n_in; (void)out_size; (void)ws_size;
    const uint32_t* xu = (const uint32_t*)d_in[0];
    float* outp = (float*)d_out;
    uint32_t* ws = (uint32_t*)d_ws;

    zero_ws<<<256, 256, 0, stream>>>(ws);
    hist_pass<<<ROWS * BPR, 256, 0, stream>>>(xu, ws);
    select1<<<ROWS, 256, 0, stream>>>(ws);
    mask_compact<<<ROWS * BPR, 256, 0, stream>>>(xu, outp, ws);
    select_fix<<<ROWS, 256, 0, stream>>>(outp, ws);
}